// Round 1
// baseline (12075.301 us; speedup 1.0000x reference)
//
#include <hip/hip_runtime.h>
#include <math.h>

// ---------------- model dims (compile-time, from reference) ----------------
constexpr int Bc  = 2;
constexpr int Tc  = 2048;
constexpr int Dc  = 1024;
constexpr int Hc  = 16;
constexpr int Lc  = 4;
constexpr int DFc = 4096;
constexpr int Vc  = 32000;
constexpr int DKc = Dc / Hc;        // 64
constexpr int Mrows = Bc * Tc;      // 4096 token rows

// ============================ embedding ============================
// x[bt, :] = wte[ids[bt], :] + wpe[bt % T, :]
__global__ __launch_bounds__(256) void embed_k(const int* __restrict__ ids,
                                               const float* __restrict__ wte,
                                               const float* __restrict__ wpe,
                                               float* __restrict__ x) {
    int bt = blockIdx.x;
    int t  = bt & (Tc - 1);            // T = 2048 (pow2)
    int id = ids[bt];
    int c  = threadIdx.x * 4;          // 256 threads * 4 floats = 1024 = D
    float4 w = *(const float4*)(wte + (size_t)id * Dc + c);
    float4 p = *(const float4*)(wpe + (size_t)t * Dc + c);
    *(float4*)(x + (size_t)bt * Dc + c) =
        make_float4(w.x + p.x, w.y + p.y, w.z + p.z, w.w + p.w);
}

// ============================ layernorm ============================
__device__ __forceinline__ float block_allreduce_sum(float v, float* tmp) {
#pragma unroll
    for (int off = 32; off > 0; off >>= 1) v += __shfl_down(v, off);
    int lane = threadIdx.x & 63, wid = threadIdx.x >> 6;
    __syncthreads();                       // protect tmp from previous use
    if (lane == 0) tmp[wid] = v;
    __syncthreads();
    return tmp[0] + tmp[1] + tmp[2] + tmp[3];
}

__global__ __launch_bounds__(256) void layernorm_k(const float* __restrict__ x,
                                                   const float* __restrict__ g,
                                                   const float* __restrict__ b,
                                                   float* __restrict__ y) {
    __shared__ float tmp[4];
    int row = blockIdx.x;
    int c   = threadIdx.x * 4;
    float4 v = *(const float4*)(x + (size_t)row * Dc + c);
    float mean = block_allreduce_sum(v.x + v.y + v.z + v.w, tmp) * (1.f / Dc);
    float dx = v.x - mean, dy = v.y - mean, dz = v.z - mean, dw = v.w - mean;
    float var = block_allreduce_sum(dx * dx + dy * dy + dz * dz + dw * dw, tmp) * (1.f / Dc);
    float inv = rsqrtf(var + 1e-5f);
    float4 gg = *(const float4*)(g + c);
    float4 bb = *(const float4*)(b + c);
    *(float4*)(y + (size_t)row * Dc + c) =
        make_float4(dx * inv * gg.x + bb.x, dy * inv * gg.y + bb.y,
                    dz * inv * gg.z + bb.z, dw * inv * gg.w + bb.w);
}

// ============================ GEMM (NT) ============================
// C[m,n] = epi( sum_k A[m,k] * W[n,k] )   A:[M,K]  W:[N,K] (torch Linear)
// EPI: 0 = none, 1 = +bias, 2 = +bias then exact GELU, 3 = +resid, 4 = +bias +resid
// 128x128 tile, BK=16, 256 threads, 8x8 micro-tile per thread.
template <int EPI>
__global__ __launch_bounds__(256) void gemm_nt(const float* __restrict__ A,
                                               const float* __restrict__ W,
                                               const float* __restrict__ bias,
                                               const float* __restrict__ resid,
                                               float* __restrict__ C,
                                               int M, int N, int K) {
    constexpr int BM = 128, BN = 128, BK = 16;
    __shared__ float As[BK][BM];   // k-major so fragment reads are float4
    __shared__ float Bs[BK][BN];
    int tid = threadIdx.x;
    int tx = tid & 15, ty = tid >> 4;
    int row0 = blockIdx.y * BM, col0 = blockIdx.x * BN;

    // staging: each thread loads 2x float4 rows of A and of W
    int lrow = tid >> 1;             // 0..127
    int lk   = (tid & 1) * 8;        // 0 or 8
    const float* Ap = A + (size_t)(row0 + lrow) * K + lk;
    const float* Wp = W + (size_t)(col0 + lrow) * K + lk;

    float acc[8][8] = {};
    for (int kt = 0; kt < K; kt += BK) {
        float4 a0 = *(const float4*)(Ap + kt);
        float4 a1 = *(const float4*)(Ap + kt + 4);
        float4 w0 = *(const float4*)(Wp + kt);
        float4 w1 = *(const float4*)(Wp + kt + 4);
        __syncthreads();             // everyone done reading previous tiles
        As[lk + 0][lrow] = a0.x; As[lk + 1][lrow] = a0.y;
        As[lk + 2][lrow] = a0.z; As[lk + 3][lrow] = a0.w;
        As[lk + 4][lrow] = a1.x; As[lk + 5][lrow] = a1.y;
        As[lk + 6][lrow] = a1.z; As[lk + 7][lrow] = a1.w;
        Bs[lk + 0][lrow] = w0.x; Bs[lk + 1][lrow] = w0.y;
        Bs[lk + 2][lrow] = w0.z; Bs[lk + 3][lrow] = w0.w;
        Bs[lk + 4][lrow] = w1.x; Bs[lk + 5][lrow] = w1.y;
        Bs[lk + 6][lrow] = w1.z; Bs[lk + 7][lrow] = w1.w;
        __syncthreads();
#pragma unroll
        for (int k = 0; k < BK; ++k) {
            float4 av0 = *(const float4*)&As[k][ty * 8];
            float4 av1 = *(const float4*)&As[k][ty * 8 + 4];
            float4 bv0 = *(const float4*)&Bs[k][tx * 8];
            float4 bv1 = *(const float4*)&Bs[k][tx * 8 + 4];
            float a[8] = {av0.x, av0.y, av0.z, av0.w, av1.x, av1.y, av1.z, av1.w};
            float bb[8] = {bv0.x, bv0.y, bv0.z, bv0.w, bv1.x, bv1.y, bv1.z, bv1.w};
#pragma unroll
            for (int i = 0; i < 8; ++i)
#pragma unroll
                for (int j = 0; j < 8; ++j)
                    acc[i][j] = fmaf(a[i], bb[j], acc[i][j]);
        }
    }
    // ---------------- epilogue ----------------
#pragma unroll
    for (int i = 0; i < 8; ++i) {
        int r = row0 + ty * 8 + i;
        size_t base = (size_t)r * N + col0 + tx * 8;
        float vals[8];
#pragma unroll
        for (int j = 0; j < 8; ++j) {
            float v = acc[i][j];
            if (EPI == 1 || EPI == 2 || EPI == 4) v += bias[col0 + tx * 8 + j];
            if (EPI == 2) v = 0.5f * v * (1.f + erff(v * 0.70710678118654752440f));
            if (EPI == 3 || EPI == 4) v += resid[base + j];
            vals[j] = v;
        }
        *(float4*)(C + base)     = make_float4(vals[0], vals[1], vals[2], vals[3]);
        *(float4*)(C + base + 4) = make_float4(vals[4], vals[5], vals[6], vals[7]);
    }
}

// ============================ attention ============================
// Flash-style causal MHA in fp32. One block = (q-tile of 32 rows, one b,h).
// 256 threads: thread t owns q-row qi=t>>3; S-entries ki = (t&7)+8j; O-cols dk0=(t&7)*8.
__global__ __launch_bounds__(256) void attn_k(const float* __restrict__ qkv,
                                              float* __restrict__ o) {
    constexpr int QB = 32, KB = 32, LDP = 72;   // LDP: pad 64->72 (16B-aligned rows, spread banks)
    __shared__ float Qs[QB][LDP];
    __shared__ float Ks[KB][LDP];
    __shared__ float Vs[KB][LDP];
    __shared__ float Ps[QB][KB + 1];

    int tid = threadIdx.x;
    int qt  = blockIdx.x;
    int bh  = blockIdx.y;
    int b = bh / Hc, h = bh % Hc;
    int q0 = qt * QB;
    const size_t rs = 3 * Dc;                       // qkv row stride
    const float* qbase = qkv + (size_t)b * Tc * rs + h * DKc;
    const float* kbase = qbase + Dc;
    const float* vbase = qbase + 2 * Dc;

    // load Q tile
    {
        int f = tid & 15, r = tid >> 4;
#pragma unroll
        for (int rr = r; rr < QB; rr += 16)
            *(float4*)&Qs[rr][f * 4] =
                *(const float4*)(qbase + (size_t)(q0 + rr) * rs + f * 4);
    }

    int qi  = tid >> 3;
    int kio = tid & 7;
    int dk0 = kio * 8;
    float m = -INFINITY, l = 0.f;
    float oacc[8] = {};
    const float scale = 0.125f;                     // 1/sqrt(64)

    for (int kt = 0; kt <= qt; ++kt) {
        int k0 = kt * KB;
        __syncthreads();                            // done reading prev K/V
        {
            int f = tid & 15, r = tid >> 4;
#pragma unroll
            for (int rr = r; rr < KB; rr += 16) {
                *(float4*)&Ks[rr][f * 4] =
                    *(const float4*)(kbase + (size_t)(k0 + rr) * rs + f * 4);
                *(float4*)&Vs[rr][f * 4] =
                    *(const float4*)(vbase + (size_t)(k0 + rr) * rs + f * 4);
            }
        }
        __syncthreads();

        // S = scale * Q K^T  (4 entries per thread)
        float s[4] = {0.f, 0.f, 0.f, 0.f};
#pragma unroll
        for (int dv = 0; dv < 16; ++dv) {
            float4 qv = *(const float4*)&Qs[qi][dv * 4];
#pragma unroll
            for (int jj = 0; jj < 4; ++jj) {
                float4 kv = *(const float4*)&Ks[kio + 8 * jj][dv * 4];
                s[jj] += qv.x * kv.x + qv.y * kv.y + qv.z * kv.z + qv.w * kv.w;
            }
        }
        // causal mask + online softmax
        float tmax = -INFINITY;
#pragma unroll
        for (int jj = 0; jj < 4; ++jj) {
            int kg = k0 + kio + 8 * jj;
            s[jj] = (kg <= q0 + qi) ? s[jj] * scale : -INFINITY;
            tmax = fmaxf(tmax, s[jj]);
        }
#pragma unroll
        for (int off = 1; off < 8; off <<= 1) tmax = fmaxf(tmax, __shfl_xor(tmax, off));
        float mnew = fmaxf(m, tmax);
        float corr = __expf(m - mnew) * 0.f + expf(m - mnew); // keep exact expf
        corr = expf(m - mnew);
        float psum = 0.f;
#pragma unroll
        for (int jj = 0; jj < 4; ++jj) {
            float p = expf(s[jj] - mnew);           // expf(-inf)=0 handles mask
            Ps[qi][kio + 8 * jj] = p;
            psum += p;
        }
#pragma unroll
        for (int off = 1; off < 8; off <<= 1) psum += __shfl_xor(psum, off);
        l = l * corr + psum;
        m = mnew;
#pragma unroll
        for (int i = 0; i < 8; ++i) oacc[i] *= corr;
        // Ps written/read by the same 8-lane group (same wave) -> no barrier needed.
        // O += P V
#pragma unroll
        for (int ki = 0; ki < KB; ++ki) {
            float p = Ps[qi][ki];
            float4 v0 = *(const float4*)&Vs[ki][dk0];
            float4 v1 = *(const float4*)&Vs[ki][dk0 + 4];
            oacc[0] = fmaf(p, v0.x, oacc[0]); oacc[1] = fmaf(p, v0.y, oacc[1]);
            oacc[2] = fmaf(p, v0.z, oacc[2]); oacc[3] = fmaf(p, v0.w, oacc[3]);
            oacc[4] = fmaf(p, v1.x, oacc[4]); oacc[5] = fmaf(p, v1.y, oacc[5]);
            oacc[6] = fmaf(p, v1.z, oacc[6]); oacc[7] = fmaf(p, v1.w, oacc[7]);
        }
    }
    float inv = 1.f / l;
    float* op = o + (size_t)(b * Tc + q0 + qi) * Dc + h * DKc + dk0;
    *(float4*)op       = make_float4(oacc[0] * inv, oacc[1] * inv, oacc[2] * inv, oacc[3] * inv);
    *(float4*)(op + 4) = make_float4(oacc[4] * inv, oacc[5] * inv, oacc[6] * inv, oacc[7] * inv);
}

// ============================ launcher ============================
extern "C" void kernel_launch(void* const* d_in, const int* in_sizes, int n_in,
                              void* d_out, int out_size, void* d_ws, size_t ws_size,
                              hipStream_t stream) {
    const int*   ids         = (const int*)d_in[0];
    const float* wte         = (const float*)d_in[1];
    const float* wpe         = (const float*)d_in[2];
    const float* c_attn_w    = (const float*)d_in[3];
    const float* attn_proj_w = (const float*)d_in[4];
    const float* ln1_g       = (const float*)d_in[5];
    const float* ln1_b       = (const float*)d_in[6];
    const float* ln2_g       = (const float*)d_in[7];
    const float* ln2_b       = (const float*)d_in[8];
    const float* fc_w        = (const float*)d_in[9];
    const float* fc_b        = (const float*)d_in[10];
    const float* proj_w      = (const float*)d_in[11];
    const float* proj_b      = (const float*)d_in[12];
    const float* lnf_g       = (const float*)d_in[13];
    const float* lnf_b       = (const float*)d_in[14];
    float* out = (float*)d_out;

    const int M = Mrows;  // 4096
    float* ws  = (float*)d_ws;
    float* x    = ws;                               // [M, D]
    float* xn   = x   + (size_t)M * Dc;             // [M, D]
    float* qkv  = xn  + (size_t)M * Dc;             // [M, 3D]
    float* oatt = qkv + (size_t)M * 3 * Dc;         // [M, D]
    float* hbuf = qkv;                              // [M, DF] aliases qkv+oatt (both dead then)

    dim3 blk(256);
    embed_k<<<M, blk, 0, stream>>>(ids, wte, wpe, x);

    for (int l = 0; l < Lc; ++l) {
        // --- attention block ---
        layernorm_k<<<M, blk, 0, stream>>>(x, ln1_g + (size_t)l * Dc, ln1_b + (size_t)l * Dc, xn);
        gemm_nt<0><<<dim3(3 * Dc / 128, M / 128), blk, 0, stream>>>(
            xn, c_attn_w + (size_t)l * 3 * Dc * Dc, nullptr, nullptr, qkv, M, 3 * Dc, Dc);
        attn_k<<<dim3(Tc / 32, Bc * Hc), blk, 0, stream>>>(qkv, oatt);
        gemm_nt<3><<<dim3(Dc / 128, M / 128), blk, 0, stream>>>(
            oatt, attn_proj_w + (size_t)l * Dc * Dc, nullptr, x, x, M, Dc, Dc);
        // --- MLP block ---
        layernorm_k<<<M, blk, 0, stream>>>(x, ln2_g + (size_t)l * Dc, ln2_b + (size_t)l * Dc, xn);
        gemm_nt<2><<<dim3(DFc / 128, M / 128), blk, 0, stream>>>(
            xn, fc_w + (size_t)l * DFc * Dc, fc_b + (size_t)l * DFc, nullptr, hbuf, M, DFc, Dc);
        gemm_nt<4><<<dim3(Dc / 128, M / 128), blk, 0, stream>>>(
            hbuf, proj_w + (size_t)l * Dc * DFc, proj_b + (size_t)l * Dc, x, x, M, Dc, DFc);
    }
    layernorm_k<<<M, blk, 0, stream>>>(x, lnf_g, lnf_b, xn);
    // weight-tied lm_head: logits = xn @ wte^T
    gemm_nt<0><<<dim3(Vc / 128, M / 128), blk, 0, stream>>>(
        xn, wte, nullptr, nullptr, out, M, Vc, Dc);
}

// Round 4
// 5480.096 us; speedup vs baseline: 2.2035x; 2.2035x over previous
//
#include <hip/hip_runtime.h>
#include <math.h>

// ---------------- model dims (compile-time, from reference) ----------------
constexpr int Bc  = 2;
constexpr int Tc  = 2048;
constexpr int Dc  = 1024;
constexpr int Hc  = 16;
constexpr int Lc  = 4;
constexpr int DFc = 4096;
constexpr int Vc  = 32000;
constexpr int DKc = Dc / Hc;        // 64
constexpr int Mrows = Bc * Tc;      // 4096 token rows

typedef _Float16 half8 __attribute__((ext_vector_type(8)));
typedef float    f32x4 __attribute__((ext_vector_type(4)));

// ============================ embedding ============================
__global__ __launch_bounds__(256) void embed_k(const int* __restrict__ ids,
                                               const float* __restrict__ wte,
                                               const float* __restrict__ wpe,
                                               float* __restrict__ x) {
    int bt = blockIdx.x;
    int t  = bt & (Tc - 1);
    int id = ids[bt];
    int c  = threadIdx.x * 4;
    float4 w = *(const float4*)(wte + (size_t)id * Dc + c);
    float4 p = *(const float4*)(wpe + (size_t)t * Dc + c);
    *(float4*)(x + (size_t)bt * Dc + c) =
        make_float4(w.x + p.x, w.y + p.y, w.z + p.z, w.w + p.w);
}

// ============================ layernorm ============================
__device__ __forceinline__ float block_allreduce_sum(float v, float* tmp) {
#pragma unroll
    for (int off = 32; off > 0; off >>= 1) v += __shfl_down(v, off);
    int lane = threadIdx.x & 63, wid = threadIdx.x >> 6;
    __syncthreads();
    if (lane == 0) tmp[wid] = v;
    __syncthreads();
    return tmp[0] + tmp[1] + tmp[2] + tmp[3];
}

__global__ __launch_bounds__(256) void layernorm_k(const float* __restrict__ x,
                                                   const float* __restrict__ g,
                                                   const float* __restrict__ b,
                                                   float* __restrict__ y) {
    __shared__ float tmp[4];
    int row = blockIdx.x;
    int c   = threadIdx.x * 4;
    float4 v = *(const float4*)(x + (size_t)row * Dc + c);
    float mean = block_allreduce_sum(v.x + v.y + v.z + v.w, tmp) * (1.f / Dc);
    float dx = v.x - mean, dy = v.y - mean, dz = v.z - mean, dw = v.w - mean;
    float var = block_allreduce_sum(dx * dx + dy * dy + dz * dz + dw * dw, tmp) * (1.f / Dc);
    float inv = rsqrtf(var + 1e-5f);
    float4 gg = *(const float4*)(g + c);
    float4 bb = *(const float4*)(b + c);
    *(float4*)(y + (size_t)row * Dc + c) =
        make_float4(dx * inv * gg.x + bb.x, dy * inv * gg.y + bb.y,
                    dz * inv * gg.z + bb.z, dw * inv * gg.w + bb.w);
}

// ============================ GEMM (NT, fp16 MFMA) ============================
// C[m,n] = epi( sum_k A[m,k] * W[n,k] ),  A:[M,K] fp32, W:[N,K] fp32 (torch Linear).
// fp32 operands converted to fp16 during reg-staging into LDS; fp32 MFMA accumulate.
// 128x128 tile, BK=32, 256 threads = 4 waves (2x2), per-wave 64x64 = 4x4 frags of 16x16.
// EPI: 0 none, 1 +bias, 2 +bias+GELU(exact), 3 +resid, 4 +bias+resid
__device__ __forceinline__ half8 cvt8(float4 x, float4 y) {
    half8 h;
    h[0] = (_Float16)x.x; h[1] = (_Float16)x.y; h[2] = (_Float16)x.z; h[3] = (_Float16)x.w;
    h[4] = (_Float16)y.x; h[5] = (_Float16)y.y; h[6] = (_Float16)y.z; h[7] = (_Float16)y.w;
    return h;
}

template <int EPI>
__global__ __launch_bounds__(256, 2) void gemm_f16(const float* __restrict__ A,
                                                   const float* __restrict__ W,
                                                   const float* __restrict__ bias,
                                                   const float* __restrict__ resid,
                                                   float* __restrict__ C,
                                                   int M, int N, int K, int mtiles) {
    constexpr int BM = 128, BN = 128, BK = 32;
    __shared__ _Float16 As[BM][BK];
    __shared__ _Float16 Bs[BN][BK];

    // XCD-chunked bijective swizzle (all grids here are %8==0), then M-major:
    // consecutive wg within an XCD chunk share the same W panel -> L2 reuse.
    int nwg = gridDim.x;
    int cpx = nwg >> 3;
    int bid = blockIdx.x;
    int wg  = (bid & 7) * cpx + (bid >> 3);
    int mt  = wg % mtiles, nt = wg / mtiles;
    int row0 = mt * BM, col0 = nt * BN;

    int t     = threadIdx.x;
    int rowL  = t >> 2;           // 0..63 (also handles rowL+64)
    int slotL = t & 3;            // 16B slot within a 32-fp16 row
    int sw    = (slotL ^ ((rowL >> 1) & 3)) * 8;   // XOR bank swizzle (elem offset)

    const float* aP = A + (size_t)(row0 + rowL) * K + slotL * 8;
    const float* bP = W + (size_t)(col0 + rowL) * K + slotL * 8;
    const size_t half_off = (size_t)64 * K;

    int wv = t >> 6, lane = t & 63;
    int wr = (wv >> 1) * 64, wc = (wv & 1) * 64;   // wave's 64x64 subtile origin
    int fr = lane & 15, kg = lane >> 4;            // frag row/col, k-group (8 elems)

    f32x4 acc[4][4] = {};

    // prologue: load tile kt=0 into registers
    float4 a0 = *(const float4*)(aP);            float4 a1 = *(const float4*)(aP + 4);
    float4 a2 = *(const float4*)(aP + half_off); float4 a3 = *(const float4*)(aP + half_off + 4);
    float4 b0 = *(const float4*)(bP);            float4 b1 = *(const float4*)(bP + 4);
    float4 b2 = *(const float4*)(bP + half_off); float4 b3 = *(const float4*)(bP + half_off + 4);

    for (int kt = 0; kt < K; kt += BK) {
        __syncthreads();                         // readers of previous tile done
        *(half8*)&As[rowL][sw]      = cvt8(a0, a1);
        *(half8*)&As[rowL + 64][sw] = cvt8(a2, a3);
        *(half8*)&Bs[rowL][sw]      = cvt8(b0, b1);
        *(half8*)&Bs[rowL + 64][sw] = cvt8(b2, b3);
        __syncthreads();
        if (kt + BK < K) {                       // issue next tile's loads early;
            int k2 = kt + BK;                    // they retire under the MFMAs below
            a0 = *(const float4*)(aP + k2);            a1 = *(const float4*)(aP + k2 + 4);
            a2 = *(const float4*)(aP + half_off + k2); a3 = *(const float4*)(aP + half_off + k2 + 4);
            b0 = *(const float4*)(bP + k2);            b1 = *(const float4*)(bP + k2 + 4);
            b2 = *(const float4*)(bP + half_off + k2); b3 = *(const float4*)(bP + half_off + k2 + 4);
        }
        half8 af[4], bf[4];
#pragma unroll
        for (int mi = 0; mi < 4; ++mi) {
            int r = wr + mi * 16 + fr;
            af[mi] = *(half8*)&As[r][(kg ^ ((r >> 1) & 3)) * 8];
        }
#pragma unroll
        for (int ni = 0; ni < 4; ++ni) {
            int c = wc + ni * 16 + fr;
            bf[ni] = *(half8*)&Bs[c][(kg ^ ((c >> 1) & 3)) * 8];
        }
#pragma unroll
        for (int mi = 0; mi < 4; ++mi)
#pragma unroll
            for (int ni = 0; ni < 4; ++ni)
                acc[mi][ni] = __builtin_amdgcn_mfma_f32_16x16x32_f16(af[mi], bf[ni], acc[mi][ni], 0, 0, 0);
    }

    // ---------------- epilogue ----------------
    // D frag layout: col = lane&15, row = (lane>>4)*4 + reg  (guide §3, m89)
    int orow = row0 + wr + (kg << 2);
    int ocol = col0 + wc + fr;
#pragma unroll
    for (int ni = 0; ni < 4; ++ni) {
        float bv = 0.f;
        if (EPI == 1 || EPI == 2 || EPI == 4) bv = bias[ocol + ni * 16];
#pragma unroll
        for (int mi = 0; mi < 4; ++mi) {
#pragma unroll
            for (int j = 0; j < 4; ++j) {
                int r = orow + mi * 16 + j;
                size_t idx = (size_t)r * N + ocol + ni * 16;
                float v = acc[mi][ni][j];
                if (EPI == 1 || EPI == 2 || EPI == 4) v += bv;
                if (EPI == 2) v = 0.5f * v * (1.f + erff(v * 0.70710678118654752440f));
                if (EPI == 3 || EPI == 4) v += resid[idx];
                C[idx] = v;
            }
        }
    }
}

// ============================ attention ============================
// Flash-style causal MHA in fp32 (unchanged from verified baseline).
__global__ __launch_bounds__(256) void attn_k(const float* __restrict__ qkv,
                                              float* __restrict__ o) {
    constexpr int QB = 32, KB = 32, LDP = 72;
    __shared__ float Qs[QB][LDP];
    __shared__ float Ks[KB][LDP];
    __shared__ float Vs[KB][LDP];
    __shared__ float Ps[QB][KB + 1];

    int tid = threadIdx.x;
    int qt  = blockIdx.x;
    int bh  = blockIdx.y;
    int b = bh / Hc, h = bh % Hc;
    int q0 = qt * QB;
    const size_t rs = 3 * Dc;
    const float* qbase = qkv + (size_t)b * Tc * rs + h * DKc;
    const float* kbase = qbase + Dc;
    const float* vbase = qbase + 2 * Dc;

    {
        int f = tid & 15, r = tid >> 4;
#pragma unroll
        for (int rr = r; rr < QB; rr += 16)
            *(float4*)&Qs[rr][f * 4] =
                *(const float4*)(qbase + (size_t)(q0 + rr) * rs + f * 4);
    }

    int qi  = tid >> 3;
    int kio = tid & 7;
    int dk0 = kio * 8;
    float m = -INFINITY, l = 0.f;
    float oacc[8] = {};
    const float scale = 0.125f;

    for (int kt = 0; kt <= qt; ++kt) {
        int k0 = kt * KB;
        __syncthreads();
        {
            int f = tid & 15, r = tid >> 4;
#pragma unroll
            for (int rr = r; rr < KB; rr += 16) {
                *(float4*)&Ks[rr][f * 4] =
                    *(const float4*)(kbase + (size_t)(k0 + rr) * rs + f * 4);
                *(float4*)&Vs[rr][f * 4] =
                    *(const float4*)(vbase + (size_t)(k0 + rr) * rs + f * 4);
            }
        }
        __syncthreads();

        float s[4] = {0.f, 0.f, 0.f, 0.f};
#pragma unroll
        for (int dv = 0; dv < 16; ++dv) {
            float4 qv = *(const float4*)&Qs[qi][dv * 4];
#pragma unroll
            for (int jj = 0; jj < 4; ++jj) {
                float4 kv = *(const float4*)&Ks[kio + 8 * jj][dv * 4];
                s[jj] += qv.x * kv.x + qv.y * kv.y + qv.z * kv.z + qv.w * kv.w;
            }
        }
        float tmax = -INFINITY;
#pragma unroll
        for (int jj = 0; jj < 4; ++jj) {
            int kg = k0 + kio + 8 * jj;
            s[jj] = (kg <= q0 + qi) ? s[jj] * scale : -INFINITY;
            tmax = fmaxf(tmax, s[jj]);
        }
#pragma unroll
        for (int off = 1; off < 8; off <<= 1) tmax = fmaxf(tmax, __shfl_xor(tmax, off));
        float mnew = fmaxf(m, tmax);
        float corr = expf(m - mnew);
        float psum = 0.f;
#pragma unroll
        for (int jj = 0; jj < 4; ++jj) {
            float p = expf(s[jj] - mnew);
            Ps[qi][kio + 8 * jj] = p;
            psum += p;
        }
#pragma unroll
        for (int off = 1; off < 8; off <<= 1) psum += __shfl_xor(psum, off);
        l = l * corr + psum;
        m = mnew;
#pragma unroll
        for (int i = 0; i < 8; ++i) oacc[i] *= corr;
#pragma unroll
        for (int ki = 0; ki < KB; ++ki) {
            float p = Ps[qi][ki];
            float4 v0 = *(const float4*)&Vs[ki][dk0];
            float4 v1 = *(const float4*)&Vs[ki][dk0 + 4];
            oacc[0] = fmaf(p, v0.x, oacc[0]); oacc[1] = fmaf(p, v0.y, oacc[1]);
            oacc[2] = fmaf(p, v0.z, oacc[2]); oacc[3] = fmaf(p, v0.w, oacc[3]);
            oacc[4] = fmaf(p, v1.x, oacc[4]); oacc[5] = fmaf(p, v1.y, oacc[5]);
            oacc[6] = fmaf(p, v1.z, oacc[6]); oacc[7] = fmaf(p, v1.w, oacc[7]);
        }
    }
    float inv = 1.f / l;
    float* op = o + (size_t)(b * Tc + q0 + qi) * Dc + h * DKc + dk0;
    *(float4*)op       = make_float4(oacc[0] * inv, oacc[1] * inv, oacc[2] * inv, oacc[3] * inv);
    *(float4*)(op + 4) = make_float4(oacc[4] * inv, oacc[5] * inv, oacc[6] * inv, oacc[7] * inv);
}

// ============================ launcher ============================
extern "C" void kernel_launch(void* const* d_in, const int* in_sizes, int n_in,
                              void* d_out, int out_size, void* d_ws, size_t ws_size,
                              hipStream_t stream) {
    const int*   ids         = (const int*)d_in[0];
    const float* wte         = (const float*)d_in[1];
    const float* wpe         = (const float*)d_in[2];
    const float* c_attn_w    = (const float*)d_in[3];
    const float* attn_proj_w = (const float*)d_in[4];
    const float* ln1_g       = (const float*)d_in[5];
    const float* ln1_b       = (const float*)d_in[6];
    const float* ln2_g       = (const float*)d_in[7];
    const float* ln2_b       = (const float*)d_in[8];
    const float* fc_w        = (const float*)d_in[9];
    const float* fc_b        = (const float*)d_in[10];
    const float* proj_w      = (const float*)d_in[11];
    const float* proj_b      = (const float*)d_in[12];
    const float* lnf_g       = (const float*)d_in[13];
    const float* lnf_b       = (const float*)d_in[14];
    float* out = (float*)d_out;

    const int M = Mrows;  // 4096
    const int MT = M / 128;
    float* ws  = (float*)d_ws;
    float* x    = ws;                               // [M, D]
    float* xn   = x   + (size_t)M * Dc;             // [M, D]
    float* qkv  = xn  + (size_t)M * Dc;             // [M, 3D]
    float* oatt = qkv + (size_t)M * 3 * Dc;         // [M, D]
    float* hbuf = qkv;                              // [M, DF] aliases qkv+oatt (both dead then)

    dim3 blk(256);
    embed_k<<<M, blk, 0, stream>>>(ids, wte, wpe, x);

    for (int l = 0; l < Lc; ++l) {
        // --- attention block ---
        layernorm_k<<<M, blk, 0, stream>>>(x, ln1_g + (size_t)l * Dc, ln1_b + (size_t)l * Dc, xn);
        gemm_f16<0><<<dim3(MT * (3 * Dc / 128)), blk, 0, stream>>>(
            xn, c_attn_w + (size_t)l * 3 * Dc * Dc, nullptr, nullptr, qkv, M, 3 * Dc, Dc, MT);
        attn_k<<<dim3(Tc / 32, Bc * Hc), blk, 0, stream>>>(qkv, oatt);
        gemm_f16<3><<<dim3(MT * (Dc / 128)), blk, 0, stream>>>(
            oatt, attn_proj_w + (size_t)l * Dc * Dc, nullptr, x, x, M, Dc, Dc, MT);
        // --- MLP block ---
        layernorm_k<<<M, blk, 0, stream>>>(x, ln2_g + (size_t)l * Dc, ln2_b + (size_t)l * Dc, xn);
        gemm_f16<2><<<dim3(MT * (DFc / 128)), blk, 0, stream>>>(
            xn, fc_w + (size_t)l * DFc * Dc, fc_b + (size_t)l * DFc, nullptr, hbuf, M, DFc, Dc, MT);
        gemm_f16<4><<<dim3(MT * (Dc / 128)), blk, 0, stream>>>(
            hbuf, proj_w + (size_t)l * Dc * DFc, proj_b + (size_t)l * Dc, x, x, M, Dc, DFc, MT);
    }
    layernorm_k<<<M, blk, 0, stream>>>(x, lnf_g, lnf_b, xn);
    // weight-tied lm_head: logits = xn @ wte^T
    gemm_f16<0><<<dim3(MT * (Vc / 128)), blk, 0, stream>>>(
        xn, wte, nullptr, nullptr, out, M, Vc, Dc, MT);
}